// Round 1
// baseline (6795.071 us; speedup 1.0000x reference)
//
#include <hip/hip_runtime.h>
#include <hip/hip_fp16.h>

#define DEVI __device__ __forceinline__

typedef __attribute__((ext_vector_type(4))) float f32x4;
typedef __attribute__((ext_vector_type(8))) short bf16x8;
typedef __attribute__((ext_vector_type(8))) _Float16 f16x8;
typedef __attribute__((ext_vector_type(2))) _Float16 f16x2;

DEVI ushort f2bf(float x) {
  union { float f; unsigned u; } v; v.f = x;
  unsigned r = v.u + 0x7fffu + ((v.u >> 16) & 1u);
  return (ushort)(r >> 16);
}
DEVI float bf2f(ushort b) {
  union { unsigned u; float f; } v; v.u = ((unsigned)b) << 16; return v.f;
}
DEVI unsigned packh2(float a, float b) {
  return ((unsigned)__half_as_ushort(__float2half(b)) << 16) |
         (unsigned)__half_as_ushort(__float2half(a));
}
DEVI float dot2(unsigned a, unsigned b, float c) {
#if __has_builtin(__builtin_amdgcn_fdot2)
  return __builtin_amdgcn_fdot2(__builtin_bit_cast(f16x2, a),
                                __builtin_bit_cast(f16x2, b), c, false);
#else
  f16x2 ha = __builtin_bit_cast(f16x2, a), hb = __builtin_bit_cast(f16x2, b);
  return c + (float)ha[0] * (float)hb[0] + (float)ha[1] * (float)hb[1];
#endif
}
DEVI float sigmoidf_(float x) { return 1.f / (1.f + __expf(-x)); }

// ---------------------------------------------------------------------------
// Generic 128x128-tile bf16 MFMA GEMM:  C[M,N] = A[M,K] @ Bw[N,K]^T + bias
// A,Bw are fp32 in gmem, converted to bf16 during LDS staging.
// SPLIT=true: hi/lo split-bf16, 3 MFMA passes (~fp32 accuracy).
// Grid: (M/128, N/128), block = 256. M fast => B-tile L2 reuse.
// ---------------------------------------------------------------------------
template<bool SPLIT>
__global__ __launch_bounds__(256)
void gemm_kernel(const float* __restrict__ A, int lda, const int* __restrict__ Aidx,
                 const float* __restrict__ Bw, int ldb,
                 const float* __restrict__ bias, float* __restrict__ C,
                 int N, int K)
{
  constexpr int BK  = SPLIT ? 32 : 64;
  constexpr int LDT = BK + 8;                  // ushort stride, keeps 16B align + bank spread
  constexpr int NV  = (128 * BK / 4) / 256;    // float4 loads / thread / operand

  __shared__ ushort Ah[128 * LDT];
  __shared__ ushort Bh[128 * LDT];
  __shared__ ushort Al[SPLIT ? 128 * LDT : 4];
  __shared__ ushort Bl[SPLIT ? 128 * LDT : 4];

  const int tid  = threadIdx.x;
  const int bm   = blockIdx.x * 128, bn = blockIdx.y * 128;
  const int lane = tid & 63, wave = tid >> 6;
  const int wr   = wave >> 1, wc = wave & 1;
  const int fr   = lane & 15, quad = lane >> 4;

  f32x4 acc[4][4] = {};

  for (int kt = 0; kt < K; kt += BK) {
    __syncthreads();
#pragma unroll
    for (int i = 0; i < NV; ++i) {
      int v   = i * 256 + tid;
      int row = v / (BK / 4);
      int c4  = (v % (BK / 4)) * 4;
      int arow = Aidx ? Aidx[bm + row] : (bm + row);
      const float4 x = *reinterpret_cast<const float4*>(A + (size_t)arow * lda + kt + c4);
      ushort4 h; h.x = f2bf(x.x); h.y = f2bf(x.y); h.z = f2bf(x.z); h.w = f2bf(x.w);
      *reinterpret_cast<ushort4*>(&Ah[row * LDT + c4]) = h;
      if (SPLIT) {
        ushort4 l;
        l.x = f2bf(x.x - bf2f(h.x)); l.y = f2bf(x.y - bf2f(h.y));
        l.z = f2bf(x.z - bf2f(h.z)); l.w = f2bf(x.w - bf2f(h.w));
        *reinterpret_cast<ushort4*>(&Al[row * LDT + c4]) = l;
      }
    }
#pragma unroll
    for (int i = 0; i < NV; ++i) {
      int v   = i * 256 + tid;
      int row = v / (BK / 4);
      int c4  = (v % (BK / 4)) * 4;
      const float4 x = *reinterpret_cast<const float4*>(Bw + (size_t)(bn + row) * ldb + kt + c4);
      ushort4 h; h.x = f2bf(x.x); h.y = f2bf(x.y); h.z = f2bf(x.z); h.w = f2bf(x.w);
      *reinterpret_cast<ushort4*>(&Bh[row * LDT + c4]) = h;
      if (SPLIT) {
        ushort4 l;
        l.x = f2bf(x.x - bf2f(h.x)); l.y = f2bf(x.y - bf2f(h.y));
        l.z = f2bf(x.z - bf2f(h.z)); l.w = f2bf(x.w - bf2f(h.w));
        *reinterpret_cast<ushort4*>(&Bl[row * LDT + c4]) = l;
      }
    }
    __syncthreads();
#pragma unroll
    for (int ks = 0; ks < BK; ks += 32) {
      bf16x8 ah[4], bh[4];
#pragma unroll
      for (int i = 0; i < 4; ++i) {
        ah[i] = *reinterpret_cast<const bf16x8*>(&Ah[(wr * 64 + i * 16 + fr) * LDT + ks + quad * 8]);
        bh[i] = *reinterpret_cast<const bf16x8*>(&Bh[(wc * 64 + i * 16 + fr) * LDT + ks + quad * 8]);
      }
      if (SPLIT) {
        bf16x8 al[4], bl[4];
#pragma unroll
        for (int i = 0; i < 4; ++i) {
          al[i] = *reinterpret_cast<const bf16x8*>(&Al[(wr * 64 + i * 16 + fr) * LDT + ks + quad * 8]);
          bl[i] = *reinterpret_cast<const bf16x8*>(&Bl[(wc * 64 + i * 16 + fr) * LDT + ks + quad * 8]);
        }
#pragma unroll
        for (int i = 0; i < 4; ++i)
#pragma unroll
          for (int j = 0; j < 4; ++j) {
            acc[i][j] = __builtin_amdgcn_mfma_f32_16x16x32_bf16(ah[i], bh[j], acc[i][j], 0, 0, 0);
            acc[i][j] = __builtin_amdgcn_mfma_f32_16x16x32_bf16(ah[i], bl[j], acc[i][j], 0, 0, 0);
            acc[i][j] = __builtin_amdgcn_mfma_f32_16x16x32_bf16(al[i], bh[j], acc[i][j], 0, 0, 0);
          }
      } else {
#pragma unroll
        for (int i = 0; i < 4; ++i)
#pragma unroll
          for (int j = 0; j < 4; ++j)
            acc[i][j] = __builtin_amdgcn_mfma_f32_16x16x32_bf16(ah[i], bh[j], acc[i][j], 0, 0, 0);
      }
    }
  }
#pragma unroll
  for (int i = 0; i < 4; ++i)
#pragma unroll
    for (int j = 0; j < 4; ++j)
#pragma unroll
      for (int r = 0; r < 4; ++r) {
        int m = bm + wr * 64 + i * 16 + quad * 4 + r;
        int n = bn + wc * 64 + j * 16 + fr;
        float vv = acc[i][j][r];
        if (bias) vv += bias[n];
        C[(size_t)m * N + n] = vv;
      }
}

// ---------------------------------------------------------------------------
// prep: WqT[e*256+d] = Wq[d*256+e];  bsum = b_ih + b_hh
// ---------------------------------------------------------------------------
__global__ void prep_kernel(const float* __restrict__ Wq, float* __restrict__ WqT,
                            const float* __restrict__ b_ih, const float* __restrict__ b_hh,
                            float* __restrict__ bsum)
{
  int idx = blockIdx.x * 256 + threadIdx.x;
  if (idx < 65536) {
    int e = idx >> 8, d = idx & 255;
    WqT[idx] = Wq[d * 256 + e];
  } else if (idx < 66560) {
    int n = idx - 65536;
    bsum[n] = b_ih[n] + b_hh[n];
  }
}

// sb[r] = keys[r,:] . bq       (8192 rows, one wave per row)
__global__ void sb_kernel(const float* __restrict__ keys, const float* __restrict__ bq,
                          float* __restrict__ sb)
{
  int row  = blockIdx.x * 4 + (threadIdx.x >> 6);
  int lane = threadIdx.x & 63;
  const float* kr = keys + (size_t)row * 256;
  float acc = kr[lane] * bq[lane] + kr[64 + lane] * bq[64 + lane]
            + kr[128 + lane] * bq[128 + lane] + kr[192 + lane] * bq[192 + lane];
#pragma unroll
  for (int off = 1; off < 64; off <<= 1) acc += __shfl_xor(acc, off);
  if (lane == 0) sb[row] = acc;
}

// ---------------------------------------------------------------------------
// Sequential scan: 128 blocks x 256 threads, all co-resident (1 block/CU).
// Block g: gate columns {2g, 2g+1} for all 16 batches (f16 MFMA, weights in regs)
//          + attention slice (b = g>>3, S-rows [64*(g&7), +64)) LDS-persistent.
// Two device-scope counter barriers per step.
// ---------------------------------------------------------------------------
#define NG 128

struct ScanSmem {
  ushort ax[16][64][8];   // f16 A-fragments of x=[ctx,h], frag-packed
  unsigned k2p[64][131];  // K2 slice, f16 pairs, pad->conflict-free
  unsigned vtp[256][35];  // values slice transposed [e][j-pair], f16 pairs
  unsigned hqp[128];      // h(t) f16 pairs for scores
  float sbs[64];
  float gout[16][16];
  float scores[256];
  float ps[64];
  unsigned psp[32];
  float wfac[16][8];
  float rcpL[16];
  float csr[16][2];       // LSTM cell state (block-owned columns)
};

__global__ __launch_bounds__(256, 1)
void scan_kernel(const float* __restrict__ E, const float* __restrict__ K2g,
                 const float* __restrict__ sbg, const float* __restrict__ valg,
                 const float* __restrict__ W_ih, const float* __restrict__ W_hh,
                 float* __restrict__ hcbuf, float* __restrict__ hglob,
                 float* __restrict__ mp, float* __restrict__ lp, float* __restrict__ up,
                 unsigned* __restrict__ ctrA, unsigned* __restrict__ ctrC)
{
  extern __shared__ char smraw[];
  ScanSmem& sm = *reinterpret_cast<ScanSmem*>(smraw);
  const int g = blockIdx.x, tid = threadIdx.x;
  const int lane = tid & 63;
  const int hc0 = g * 2;
  const int bC = g >> 3, ss = g & 7, j0 = ss * 64;

  // ---- persistent LDS init: K2 slice (f16 pairs), valuesT slice, sb slice
  for (int idx = tid; idx < 64 * 128; idx += 256) {
    int j = idx >> 7, i = idx & 127;
    const float* src = K2g + (size_t)(bC * 512 + j0 + j) * 256 + 2 * i;
    sm.k2p[j][i] = packh2(src[0], src[1]);
  }
  for (int it = 0; it < 32; ++it) {   // e fast within iteration -> coalesced
    int e = tid, jp = it;
    float v0 = valg[(size_t)(bC * 512 + j0 + 2 * jp) * 256 + e];
    float v1 = valg[(size_t)(bC * 512 + j0 + 2 * jp + 1) * 256 + e];
    sm.vtp[e][jp] = packh2(v0, v1);
  }
  if (tid < 64) sm.sbs[tid] = sbg[bC * 512 + j0 + tid];
  if (tid < 32) sm.csr[tid >> 1][tid & 1] = 0.f;

  // ---- gate-weight B-fragments in registers (wave 0 uses them)
  f16x8 bfrag[16];
  {
    int n = lane & 15, quad = lane >> 4;
    int q2 = n >> 1, c = n & 1;
    int grow = q2 * 256 + hc0 + c;
    for (int gk = 0; gk < 16; ++gk) {
      f16x8 f;
#pragma unroll
      for (int jj = 0; jj < 8; ++jj) {
        int k = gk * 32 + quad * 8 + jj;
        float w = 0.f;
        if (n < 8) w = (k < 256) ? W_ih[(size_t)grow * 512 + 256 + k]
                                 : W_hh[(size_t)grow * 256 + (k - 256)];
        f[jj] = (_Float16)w;
      }
      bfrag[gk] = f;
    }
  }
  __syncthreads();

  const int HS = 16 * 256;
  for (int t = 0; t <= 128; ++t) {
    if (t == 0) {
      for (int idx = tid; idx < 4096; idx += 256)
        reinterpret_cast<unsigned*>(sm.ax)[idx] = 0u;   // ctx0 = h0 = 0
    } else {
      if (tid == 0) {
        while (__hip_atomic_load(&ctrC[t - 1], __ATOMIC_RELAXED, __HIP_MEMORY_SCOPE_AGENT) < NG)
          __builtin_amdgcn_s_sleep(1);
      }
      __syncthreads();
      __builtin_amdgcn_fence(__ATOMIC_ACQUIRE, "agent");
      if (tid < 16) {       // per-batch softmax combine factors
        int b = tid;
        float mv[8], M = -1e30f;
#pragma unroll
        for (int u8 = 0; u8 < 8; ++u8) { mv[u8] = mp[b * 8 + u8]; M = fmaxf(M, mv[u8]); }
        float L = 0.f;
#pragma unroll
        for (int u8 = 0; u8 < 8; ++u8) {
          float w = __expf(mv[u8] - M);
          sm.wfac[b][u8] = w;
          L += lp[b * 8 + u8] * w;
        }
        sm.rcpL[b] = 1.f / L;
      }
      __syncthreads();
      const float* hsrc = hglob + ((t - 1) & 1) * HS;
      for (int idx = tid; idx < 4096; idx += 256) {
        int b = idx >> 8, e = idx & 255;
        const float* ub = up + (size_t)b * 2048 + e;
        float acc2 = 0.f;
#pragma unroll
        for (int u8 = 0; u8 < 8; ++u8) acc2 = fmaf(ub[u8 * 256], sm.wfac[b][u8], acc2);
        float cx = acc2 * sm.rcpL[b];
        sm.ax[e >> 5][(((e >> 3) & 3) << 4) | b][e & 7] = __half_as_ushort(__float2half(cx));
        if (g == b) hcbuf[(size_t)(b * 128 + (t - 1)) * 512 + 256 + e] = cx;
        float hv = hsrc[idx];
        sm.ax[8 + (e >> 5)][(((e >> 3) & 3) << 4) | b][e & 7] = __half_as_ushort(__float2half(hv));
      }
    }
    if (t == 128) break;
    __syncthreads();

    // ---- gates via f16 MFMA (wave 0): D[b][r] = sum_k x[b][k] * W[r][k]
    if (tid < 64) {
      f32x4 acc2 = {0.f, 0.f, 0.f, 0.f};
#pragma unroll
      for (int gk = 0; gk < 16; ++gk) {
        f16x8 a = *reinterpret_cast<const f16x8*>(&sm.ax[gk][lane][0]);
        acc2 = __builtin_amdgcn_mfma_f32_16x16x32_f16(a, bfrag[gk], acc2, 0, 0, 0);
      }
      int n = lane & 15, quad = lane >> 4;
#pragma unroll
      for (int r = 0; r < 4; ++r) sm.gout[quad * 4 + r][n] = acc2[r];
    }
    __syncthreads();

    // ---- LSTM pointwise (tid<32): (b, c)
    if (tid < 32) {
      int b = tid >> 1, c = tid & 1;
      const float* Erow = E + (size_t)(b * 128 + t) * 1024 + hc0 + c;
      float gi = sm.gout[b][0 + c] + Erow[0];
      float gf = sm.gout[b][2 + c] + Erow[256];
      float gg = sm.gout[b][4 + c] + Erow[512];
      float go = sm.gout[b][6 + c] + Erow[768];
      float iv = sigmoidf_(gi), fv = sigmoidf_(gf), gv = tanhf(gg), ov = sigmoidf_(go);
      float cn = fv * sm.csr[b][c] + iv * gv;
      sm.csr[b][c] = cn;
      float hn = ov * tanhf(cn);
      hglob[(t & 1) * HS + b * 256 + hc0 + c] = hn;
      hcbuf[(size_t)(b * 128 + t) * 512 + hc0 + c] = hn;
    }
    __syncthreads();
    __builtin_amdgcn_fence(__ATOMIC_RELEASE, "agent");
    if (tid == 0) {
      __hip_atomic_fetch_add(&ctrA[t], 1u, __ATOMIC_RELEASE, __HIP_MEMORY_SCOPE_AGENT);
      while (__hip_atomic_load(&ctrA[t], __ATOMIC_RELAXED, __HIP_MEMORY_SCOPE_AGENT) < NG)
        __builtin_amdgcn_s_sleep(1);
    }
    __syncthreads();
    __builtin_amdgcn_fence(__ATOMIC_ACQUIRE, "agent");

    // ---- attention slice: scores = K2slice . h(t) + sb ; online softmax partials
    if (tid < 128) {
      const float* hh = hglob + (t & 1) * HS + bC * 256;
      sm.hqp[tid] = packh2(hh[2 * tid], hh[2 * tid + 1]);
    }
    __syncthreads();
    {
      int j = tid & 63, q = tid >> 6;
      float acc2 = 0.f;
#pragma unroll
      for (int i = 0; i < 32; ++i) {
        int ii = q * 32 + i;
        acc2 = dot2(sm.k2p[j][ii], sm.hqp[ii], acc2);
      }
      sm.scores[tid] = acc2;
    }
    __syncthreads();
    if (tid < 64) {
      float s = sm.scores[tid] + sm.scores[64 + tid] + sm.scores[128 + tid]
              + sm.scores[192 + tid] + sm.sbs[tid];
      float mx = s;
#pragma unroll
      for (int off = 1; off < 64; off <<= 1) mx = fmaxf(mx, __shfl_xor(mx, off));
      float p = __expf(s - mx);
      float ls = p;
#pragma unroll
      for (int off = 1; off < 64; off <<= 1) ls += __shfl_xor(ls, off);
      sm.ps[tid] = p;
      if (tid == 0) { mp[bC * 8 + ss] = mx; lp[bC * 8 + ss] = ls; }
    }
    __syncthreads();
    if (tid < 32) sm.psp[tid] = packh2(sm.ps[2 * tid], sm.ps[2 * tid + 1]);
    __syncthreads();
    {
      float acc2 = 0.f;
#pragma unroll
      for (int jp = 0; jp < 32; ++jp) acc2 = dot2(sm.psp[jp], sm.vtp[tid][jp], acc2);
      up[(size_t)(bC * 8 + ss) * 256 + tid] = acc2;
    }
    __syncthreads();
    __builtin_amdgcn_fence(__ATOMIC_RELEASE, "agent");
    if (tid == 0)
      __hip_atomic_fetch_add(&ctrC[t], 1u, __ATOMIC_RELEASE, __HIP_MEMORY_SCOPE_AGENT);
  }
}

// ---------------------------------------------------------------------------
extern "C" void kernel_launch(void* const* d_in, const int* in_sizes, int n_in,
                              void* d_out, int out_size, void* d_ws, size_t ws_size,
                              hipStream_t stream)
{
  const int*   inputs   = (const int*)  d_in[0];
  const float* features = (const float*)d_in[1];
  const float* emb      = (const float*)d_in[2];
  const float* W_ih     = (const float*)d_in[3];
  const float* W_hh     = (const float*)d_in[4];
  const float* b_ih     = (const float*)d_in[5];
  const float* b_hh     = (const float*)d_in[6];
  const float* Wq       = (const float*)d_in[7];
  const float* bq       = (const float*)d_in[8];
  const float* Wk       = (const float*)d_in[9];
  const float* bk       = (const float*)d_in[10];
  const float* Wv       = (const float*)d_in[11];
  const float* bv       = (const float*)d_in[12];
  const float* Wo       = (const float*)d_in[13];
  const float* bo       = (const float*)d_in[14];
  float* out = (float*)d_out;

  char* ws = (char*)d_ws;
  size_t off = 0;
  auto alloc = [&](size_t bytes) -> char* {
    char* p = ws + off;
    off += (bytes + 255) & ~size_t(255);
    return p;
  };
  float*    keys  = (float*)   alloc((size_t)8192 * 256 * 4);
  float*    vals  = (float*)   alloc((size_t)8192 * 256 * 4);
  float*    K2    = (float*)   alloc((size_t)8192 * 256 * 4);
  float*    E     = (float*)   alloc((size_t)2048 * 1024 * 4);
  float*    WqT   = (float*)   alloc((size_t)256 * 256 * 4);
  float*    sb    = (float*)   alloc((size_t)8192 * 4);
  float*    bsum  = (float*)   alloc((size_t)1024 * 4);
  float*    hcbuf = (float*)   alloc((size_t)2048 * 512 * 4);
  float*    hglob = (float*)   alloc((size_t)2 * 16 * 256 * 4);
  float*    mp    = (float*)   alloc((size_t)16 * 8 * 4);
  float*    lp    = (float*)   alloc((size_t)16 * 8 * 4);
  float*    up    = (float*)   alloc((size_t)16 * 8 * 256 * 4);
  unsigned* ctrA  = (unsigned*)alloc((size_t)128 * 4);
  unsigned* ctrC  = (unsigned*)alloc((size_t)128 * 4);

  hipMemsetAsync(ctrA, 0, 128 * 4, stream);
  hipMemsetAsync(ctrC, 0, 128 * 4, stream);

  prep_kernel<<<260, 256, 0, stream>>>(Wq, WqT, b_ih, b_hh, bsum);

  // keys = features @ Wk^T + bk      [8192 x 256], K=512
  gemm_kernel<true><<<dim3(64, 2), 256, 0, stream>>>(features, 512, nullptr, Wk, 512, bk, keys, 256, 512);
  // values = features @ Wv^T + bv
  gemm_kernel<true><<<dim3(64, 2), 256, 0, stream>>>(features, 512, nullptr, Wv, 512, bv, vals, 256, 512);
  // K2 = keys @ Wq  (B = WqT so that B[n][k] = Wq[k][n])
  gemm_kernel<true><<<dim3(64, 2), 256, 0, stream>>>(keys, 256, nullptr, WqT, 256, nullptr, K2, 256, 256);
  // sb = keys . bq
  sb_kernel<<<2048, 256, 0, stream>>>(keys, bq, sb);
  // E = emb[inputs] @ W_ih[:, :256]^T + (b_ih + b_hh)   [2048 x 1024], K=256
  gemm_kernel<true><<<dim3(16, 8), 256, 0, stream>>>(emb, 256, inputs, W_ih, 512, bsum, E, 1024, 256);

  // sequential scan
  hipFuncSetAttribute(reinterpret_cast<const void*>(scan_kernel),
                      hipFuncAttributeMaxDynamicSharedMemorySize, (int)sizeof(ScanSmem));
  scan_kernel<<<NG, 256, sizeof(ScanSmem), stream>>>(E, K2, sb, vals, W_ih, W_hh,
                                                     hcbuf, hglob, mp, lp, up, ctrA, ctrC);

  // out = [h, ctx] @ Wo^T + bo       [2048 x 32000], K=512
  gemm_kernel<false><<<dim3(16, 250), 256, 0, stream>>>(hcbuf, 512, nullptr, Wo, 512, bo, out, 32000, 512);
}

// Round 2
// 2758.271 us; speedup vs baseline: 2.4635x; 2.4635x over previous
//
#include <hip/hip_runtime.h>
#include <hip/hip_fp16.h>

#define DEVI __device__ __forceinline__

typedef __attribute__((ext_vector_type(4))) float f32x4;
typedef __attribute__((ext_vector_type(8))) short bf16x8;
typedef __attribute__((ext_vector_type(8))) _Float16 f16x8;
typedef __attribute__((ext_vector_type(2))) _Float16 f16x2;

DEVI ushort f2bf(float x) {
  union { float f; unsigned u; } v; v.f = x;
  unsigned r = v.u + 0x7fffu + ((v.u >> 16) & 1u);
  return (ushort)(r >> 16);
}
DEVI float bf2f(ushort b) {
  union { unsigned u; float f; } v; v.u = ((unsigned)b) << 16; return v.f;
}
DEVI unsigned packh2(float a, float b) {
  return ((unsigned)__half_as_ushort(__float2half(b)) << 16) |
         (unsigned)__half_as_ushort(__float2half(a));
}
DEVI float dot2(unsigned a, unsigned b, float c) {
#if __has_builtin(__builtin_amdgcn_fdot2)
  return __builtin_amdgcn_fdot2(__builtin_bit_cast(f16x2, a),
                                __builtin_bit_cast(f16x2, b), c, false);
#else
  f16x2 ha = __builtin_bit_cast(f16x2, a), hb = __builtin_bit_cast(f16x2, b);
  return c + (float)ha[0] * (float)hb[0] + (float)ha[1] * (float)hb[1];
#endif
}
DEVI float sigmoidf_(float x) { return 1.f / (1.f + __expf(-x)); }

// relaxed agent-scope (sc0 sc1) accesses — coherence-point ops, NO cache-walk
DEVI void gstore(float* p, float v) {
  __hip_atomic_store(p, v, __ATOMIC_RELAXED, __HIP_MEMORY_SCOPE_AGENT);
}
DEVI float gload(const float* p) {
  return __hip_atomic_load(p, __ATOMIC_RELAXED, __HIP_MEMORY_SCOPE_AGENT);
}
DEVI void gstoreu(unsigned* p, unsigned v) {
  __hip_atomic_store(p, v, __ATOMIC_RELAXED, __HIP_MEMORY_SCOPE_AGENT);
}
DEVI unsigned gloadu(const unsigned* p) {
  return __hip_atomic_load(p, __ATOMIC_RELAXED, __HIP_MEMORY_SCOPE_AGENT);
}

// ---------------------------------------------------------------------------
// Generic 128x128-tile bf16 MFMA GEMM:  C[M,N] = A[M,K] @ Bw[N,K]^T + bias
// SPLIT=true: hi/lo split-bf16, 3 MFMA passes (~fp32 accuracy).
// ABF16=true: A is already bf16 (ushort) in gmem.
// ---------------------------------------------------------------------------
template<bool SPLIT, bool ABF16>
__global__ __launch_bounds__(256)
void gemm_kernel(const void* __restrict__ A_, int lda, const int* __restrict__ Aidx,
                 const float* __restrict__ Bw, int ldb,
                 const float* __restrict__ bias, float* __restrict__ C,
                 int N, int K)
{
  constexpr int BK  = SPLIT ? 32 : 64;
  constexpr int LDT = BK + 8;
  constexpr int NV  = (128 * BK / 4) / 256;

  __shared__ ushort Ah[128 * LDT];
  __shared__ ushort Bh[128 * LDT];
  __shared__ ushort Al[SPLIT ? 128 * LDT : 4];
  __shared__ ushort Bl[SPLIT ? 128 * LDT : 4];

  const int tid  = threadIdx.x;
  const int bm   = blockIdx.x * 128, bn = blockIdx.y * 128;
  const int lane = tid & 63, wave = tid >> 6;
  const int wr   = wave >> 1, wc = wave & 1;
  const int fr   = lane & 15, quad = lane >> 4;

  f32x4 acc[4][4] = {};

  for (int kt = 0; kt < K; kt += BK) {
    __syncthreads();
#pragma unroll
    for (int i = 0; i < NV; ++i) {
      int v   = i * 256 + tid;
      int row = v / (BK / 4);
      int c4  = (v % (BK / 4)) * 4;
      int arow = Aidx ? Aidx[bm + row] : (bm + row);
      if (ABF16) {
        const ushort* A = (const ushort*)A_;
        ushort4 h = *reinterpret_cast<const ushort4*>(A + (size_t)arow * lda + kt + c4);
        *reinterpret_cast<ushort4*>(&Ah[row * LDT + c4]) = h;
      } else {
        const float* A = (const float*)A_;
        const float4 x = *reinterpret_cast<const float4*>(A + (size_t)arow * lda + kt + c4);
        ushort4 h; h.x = f2bf(x.x); h.y = f2bf(x.y); h.z = f2bf(x.z); h.w = f2bf(x.w);
        *reinterpret_cast<ushort4*>(&Ah[row * LDT + c4]) = h;
        if (SPLIT) {
          ushort4 l;
          l.x = f2bf(x.x - bf2f(h.x)); l.y = f2bf(x.y - bf2f(h.y));
          l.z = f2bf(x.z - bf2f(h.z)); l.w = f2bf(x.w - bf2f(h.w));
          *reinterpret_cast<ushort4*>(&Al[row * LDT + c4]) = l;
        }
      }
    }
#pragma unroll
    for (int i = 0; i < NV; ++i) {
      int v   = i * 256 + tid;
      int row = v / (BK / 4);
      int c4  = (v % (BK / 4)) * 4;
      const float4 x = *reinterpret_cast<const float4*>(Bw + (size_t)(bn + row) * ldb + kt + c4);
      ushort4 h; h.x = f2bf(x.x); h.y = f2bf(x.y); h.z = f2bf(x.z); h.w = f2bf(x.w);
      *reinterpret_cast<ushort4*>(&Bh[row * LDT + c4]) = h;
      if (SPLIT) {
        ushort4 l;
        l.x = f2bf(x.x - bf2f(h.x)); l.y = f2bf(x.y - bf2f(h.y));
        l.z = f2bf(x.z - bf2f(h.z)); l.w = f2bf(x.w - bf2f(h.w));
        *reinterpret_cast<ushort4*>(&Bl[row * LDT + c4]) = l;
      }
    }
    __syncthreads();
#pragma unroll
    for (int ks = 0; ks < BK; ks += 32) {
      bf16x8 ah[4], bh[4];
#pragma unroll
      for (int i = 0; i < 4; ++i) {
        ah[i] = *reinterpret_cast<const bf16x8*>(&Ah[(wr * 64 + i * 16 + fr) * LDT + ks + quad * 8]);
        bh[i] = *reinterpret_cast<const bf16x8*>(&Bh[(wc * 64 + i * 16 + fr) * LDT + ks + quad * 8]);
      }
      if (SPLIT) {
        bf16x8 al[4], bl[4];
#pragma unroll
        for (int i = 0; i < 4; ++i) {
          al[i] = *reinterpret_cast<const bf16x8*>(&Al[(wr * 64 + i * 16 + fr) * LDT + ks + quad * 8]);
          bl[i] = *reinterpret_cast<const bf16x8*>(&Bl[(wc * 64 + i * 16 + fr) * LDT + ks + quad * 8]);
        }
#pragma unroll
        for (int i = 0; i < 4; ++i)
#pragma unroll
          for (int j = 0; j < 4; ++j) {
            acc[i][j] = __builtin_amdgcn_mfma_f32_16x16x32_bf16(ah[i], bh[j], acc[i][j], 0, 0, 0);
            acc[i][j] = __builtin_amdgcn_mfma_f32_16x16x32_bf16(ah[i], bl[j], acc[i][j], 0, 0, 0);
            acc[i][j] = __builtin_amdgcn_mfma_f32_16x16x32_bf16(al[i], bh[j], acc[i][j], 0, 0, 0);
          }
      } else {
#pragma unroll
        for (int i = 0; i < 4; ++i)
#pragma unroll
          for (int j = 0; j < 4; ++j)
            acc[i][j] = __builtin_amdgcn_mfma_f32_16x16x32_bf16(ah[i], bh[j], acc[i][j], 0, 0, 0);
      }
    }
  }
#pragma unroll
  for (int i = 0; i < 4; ++i)
#pragma unroll
    for (int j = 0; j < 4; ++j)
#pragma unroll
      for (int r = 0; r < 4; ++r) {
        int m = bm + wr * 64 + i * 16 + quad * 4 + r;
        int n = bn + wc * 64 + j * 16 + fr;
        float vv = acc[i][j][r];
        if (bias) vv += bias[n];
        C[(size_t)m * N + n] = vv;
      }
}

// ---------------------------------------------------------------------------
__global__ void prep_kernel(const float* __restrict__ Wq, float* __restrict__ WqT,
                            const float* __restrict__ b_ih, const float* __restrict__ b_hh,
                            float* __restrict__ bsum)
{
  int idx = blockIdx.x * 256 + threadIdx.x;
  if (idx < 65536) {
    int e = idx >> 8, d = idx & 255;
    WqT[idx] = Wq[d * 256 + e];
  } else if (idx < 66560) {
    int n = idx - 65536;
    bsum[n] = b_ih[n] + b_hh[n];
  }
}

// sb[r] = keys[r,:] . bq
__global__ void sb_kernel(const float* __restrict__ keys, const float* __restrict__ bq,
                          float* __restrict__ sb)
{
  int row  = blockIdx.x * 4 + (threadIdx.x >> 6);
  int lane = threadIdx.x & 63;
  const float* kr = keys + (size_t)row * 256;
  float acc = kr[lane] * bq[lane] + kr[64 + lane] * bq[64 + lane]
            + kr[128 + lane] * bq[128 + lane] + kr[192 + lane] * bq[192 + lane];
#pragma unroll
  for (int off = 1; off < 64; off <<= 1) acc += __shfl_xor(acc, off);
  if (lane == 0) sb[row] = acc;
}

// f32 -> bf16 convert (for final-GEMM A operand)
__global__ void cvt_kernel(const float* __restrict__ src, ushort* __restrict__ dst, int n4)
{
  int i = blockIdx.x * 256 + threadIdx.x;
  if (i < n4) {
    float4 x = reinterpret_cast<const float4*>(src)[i];
    ushort4 h; h.x = f2bf(x.x); h.y = f2bf(x.y); h.z = f2bf(x.z); h.w = f2bf(x.w);
    reinterpret_cast<ushort4*>(dst)[i] = h;
  }
}

// ---------------------------------------------------------------------------
// Sequential scan: 128 blocks x 256 threads, all co-resident (1 block/CU).
// Sync: flag-per-block arrays, relaxed agent-scope (sc0sc1) atomics ONLY —
// no fences / no release atomics (those lower to buffer_wbl2/buffer_inv =
// full L2 writeback/invalidate walks, the round-1 46 us/step stall).
// __syncthreads() before each flag store provides the vmcnt(0) drain.
// ---------------------------------------------------------------------------
#define NG 128

struct ScanSmem {
  ushort ax[16][64][8];   // f16 A-fragments of x=[ctx,h]
  unsigned k2p[64][131];  // K2 slice, f16 pairs
  unsigned vtp[256][35];  // values slice transposed [e][j-pair]
  unsigned hqp[128];      // h(t) f16 pairs
  float sbs[64];
  float gout[16][16];
  float scores[256];
  float ps[64];
  unsigned psp[32];
  float wfac[16][8];
  float rcpL[16];
  float csr[16][2];
};

__global__ __launch_bounds__(256, 1)
void scan_kernel(const float* __restrict__ E, const float* __restrict__ K2g,
                 const float* __restrict__ sbg, const float* __restrict__ valg,
                 const float* __restrict__ W_ih, const float* __restrict__ W_hh,
                 float* __restrict__ hcbuf, float* __restrict__ hglob,
                 float* __restrict__ mp, float* __restrict__ lp,
                 unsigned* __restrict__ up_p,
                 unsigned* __restrict__ flagA, unsigned* __restrict__ flagC)
{
  extern __shared__ char smraw[];
  ScanSmem& sm = *reinterpret_cast<ScanSmem*>(smraw);
  const int g = blockIdx.x, tid = threadIdx.x;
  const int lane = tid & 63;
  const int hc0 = g * 2;
  const int bC = g >> 3, ss = g & 7, j0 = ss * 64;

  // persistent LDS init
  for (int idx = tid; idx < 64 * 128; idx += 256) {
    int j = idx >> 7, i = idx & 127;
    const float* src = K2g + (size_t)(bC * 512 + j0 + j) * 256 + 2 * i;
    sm.k2p[j][i] = packh2(src[0], src[1]);
  }
  for (int it = 0; it < 32; ++it) {
    int e = tid, jp = it;
    float v0 = valg[(size_t)(bC * 512 + j0 + 2 * jp) * 256 + e];
    float v1 = valg[(size_t)(bC * 512 + j0 + 2 * jp + 1) * 256 + e];
    sm.vtp[e][jp] = packh2(v0, v1);
  }
  if (tid < 64) sm.sbs[tid] = sbg[bC * 512 + j0 + tid];
  if (tid < 32) sm.csr[tid >> 1][tid & 1] = 0.f;

  // gate-weight B-fragments in registers (wave 0)
  f16x8 bfrag[16];
  {
    int n = lane & 15, quad = lane >> 4;
    int q2 = n >> 1, c = n & 1;
    int grow = q2 * 256 + hc0 + c;
    for (int gk = 0; gk < 16; ++gk) {
      f16x8 f;
#pragma unroll
      for (int jj = 0; jj < 8; ++jj) {
        int k = gk * 32 + quad * 8 + jj;
        float w = 0.f;
        if (n < 8) w = (k < 256) ? W_ih[(size_t)grow * 512 + 256 + k]
                                 : W_hh[(size_t)grow * 256 + (k - 256)];
        f[jj] = (_Float16)w;
      }
      bfrag[gk] = f;
    }
  }
  __syncthreads();

  const int HS = 16 * 256;
  for (int t = 0; t <= 128; ++t) {
    if (t == 0) {
      for (int idx = tid; idx < 4096; idx += 256)
        reinterpret_cast<unsigned*>(sm.ax)[idx] = 0u;
    } else {
      // ---- barrier C(t-1): parallel per-slot spin
      if (tid < NG) {
        while (gloadu(&flagC[tid]) < (unsigned)t) __builtin_amdgcn_s_sleep(2);
      }
      __syncthreads();
      if (tid < 16) {
        int b = tid;
        float mv[8], M = -1e30f;
#pragma unroll
        for (int u8 = 0; u8 < 8; ++u8) { mv[u8] = gload(&mp[b * 8 + u8]); M = fmaxf(M, mv[u8]); }
        float L = 0.f;
#pragma unroll
        for (int u8 = 0; u8 < 8; ++u8) {
          float w = __expf(mv[u8] - M);
          sm.wfac[b][u8] = w;
          L += gload(&lp[b * 8 + u8]) * w;
        }
        sm.rcpL[b] = 1.f / L;
      }
      __syncthreads();
      const float* hsrc = hglob + ((t - 1) & 1) * HS;
      for (int pidx = tid; pidx < 2048; pidx += 256) {
        int b = pidx >> 7, ep = pidx & 127, e0 = ep * 2;
        float a0 = 0.f, a1 = 0.f;
#pragma unroll
        for (int u8 = 0; u8 < 8; ++u8) {
          unsigned pv = gloadu(&up_p[(size_t)(b * 8 + u8) * 128 + ep]);
          f16x2 hp = __builtin_bit_cast(f16x2, pv);
          float w = sm.wfac[b][u8];
          a0 = fmaf((float)hp[0], w, a0);
          a1 = fmaf((float)hp[1], w, a1);
        }
        float r = sm.rcpL[b];
        float cx0 = a0 * r, cx1 = a1 * r;
        int gk = e0 >> 5, row = (((e0 >> 3) & 3) << 4) | b, c = e0 & 7;
        sm.ax[gk][row][c]     = __half_as_ushort(__float2half(cx0));
        sm.ax[gk][row][c + 1] = __half_as_ushort(__float2half(cx1));
        if (g == b) {
          float* dst = &hcbuf[(size_t)(b * 128 + (t - 1)) * 512 + 256 + e0];
          dst[0] = cx0; dst[1] = cx1;
        }
        float hv0 = gload(&hsrc[b * 256 + e0]);
        float hv1 = gload(&hsrc[b * 256 + e0 + 1]);
        sm.ax[8 + gk][row][c]     = __half_as_ushort(__float2half(hv0));
        sm.ax[8 + gk][row][c + 1] = __half_as_ushort(__float2half(hv1));
      }
    }
    if (t == 128) break;
    __syncthreads();

    // ---- gates via f16 MFMA (wave 0)
    if (tid < 64) {
      f32x4 acc2 = {0.f, 0.f, 0.f, 0.f};
#pragma unroll
      for (int gk = 0; gk < 16; ++gk) {
        f16x8 a = *reinterpret_cast<const f16x8*>(&sm.ax[gk][lane][0]);
        acc2 = __builtin_amdgcn_mfma_f32_16x16x32_f16(a, bfrag[gk], acc2, 0, 0, 0);
      }
      int n = lane & 15, quad = lane >> 4;
#pragma unroll
      for (int r = 0; r < 4; ++r) sm.gout[quad * 4 + r][n] = acc2[r];
    }
    __syncthreads();

    // ---- LSTM pointwise
    if (tid < 32) {
      int b = tid >> 1, c = tid & 1;
      const float* Erow = E + (size_t)(b * 128 + t) * 1024 + hc0 + c;
      float gi = sm.gout[b][0 + c] + Erow[0];
      float gf = sm.gout[b][2 + c] + Erow[256];
      float gg = sm.gout[b][4 + c] + Erow[512];
      float go = sm.gout[b][6 + c] + Erow[768];
      float iv = sigmoidf_(gi), fv = sigmoidf_(gf), gv = tanhf(gg), ov = sigmoidf_(go);
      float cn = fv * sm.csr[b][c] + iv * gv;
      sm.csr[b][c] = cn;
      float hn = ov * tanhf(cn);
      gstore(&hglob[(t & 1) * HS + b * 256 + hc0 + c], hn);
      hcbuf[(size_t)(b * 128 + t) * 512 + hc0 + c] = hn;
    }
    // ---- barrier A(t): syncthreads drains stores (vmcnt(0) before s_barrier)
    __syncthreads();
    if (tid == 0) gstoreu(&flagA[g], (unsigned)(t + 1));
    if (tid < NG) {
      while (gloadu(&flagA[tid]) < (unsigned)(t + 1)) __builtin_amdgcn_s_sleep(2);
    }
    __syncthreads();

    // ---- attention slice
    if (tid < 128) {
      const float* hh = hglob + (t & 1) * HS + bC * 256;
      float h0 = gload(&hh[2 * tid]);
      float h1 = gload(&hh[2 * tid + 1]);
      sm.hqp[tid] = packh2(h0, h1);
    }
    __syncthreads();
    {
      int j = tid & 63, q = tid >> 6;
      float acc2 = 0.f;
#pragma unroll
      for (int i = 0; i < 32; ++i) {
        int ii = q * 32 + i;
        acc2 = dot2(sm.k2p[j][ii], sm.hqp[ii], acc2);
      }
      sm.scores[tid] = acc2;
    }
    __syncthreads();
    if (tid < 64) {
      float s = sm.scores[tid] + sm.scores[64 + tid] + sm.scores[128 + tid]
              + sm.scores[192 + tid] + sm.sbs[tid];
      float mx = s;
#pragma unroll
      for (int off = 1; off < 64; off <<= 1) mx = fmaxf(mx, __shfl_xor(mx, off));
      float p = __expf(s - mx);
      float ls = p;
#pragma unroll
      for (int off = 1; off < 64; off <<= 1) ls += __shfl_xor(ls, off);
      sm.ps[tid] = p;
      if (tid == 0) {
        gstore(&mp[bC * 8 + ss], mx);
        gstore(&lp[bC * 8 + ss], ls);
      }
    }
    __syncthreads();
    if (tid < 32) sm.psp[tid] = packh2(sm.ps[2 * tid], sm.ps[2 * tid + 1]);
    __syncthreads();
    {
      float acc2 = 0.f;
#pragma unroll
      for (int jp = 0; jp < 32; ++jp) acc2 = dot2(sm.psp[jp], sm.vtp[tid][jp], acc2);
      float other = __shfl_xor(acc2, 1);
      if (!(tid & 1))
        gstoreu(&up_p[(size_t)(bC * 8 + ss) * 128 + (tid >> 1)], packh2(acc2, other));
    }
    // ---- barrier C(t) arrive (spin deferred to next step's top)
    __syncthreads();
    if (tid == 0) gstoreu(&flagC[g], (unsigned)(t + 1));
  }
}

// ---------------------------------------------------------------------------
extern "C" void kernel_launch(void* const* d_in, const int* in_sizes, int n_in,
                              void* d_out, int out_size, void* d_ws, size_t ws_size,
                              hipStream_t stream)
{
  const int*   inputs   = (const int*)  d_in[0];
  const float* features = (const float*)d_in[1];
  const float* emb      = (const float*)d_in[2];
  const float* W_ih     = (const float*)d_in[3];
  const float* W_hh     = (const float*)d_in[4];
  const float* b_ih     = (const float*)d_in[5];
  const float* b_hh     = (const float*)d_in[6];
  const float* Wq       = (const float*)d_in[7];
  const float* bq       = (const float*)d_in[8];
  const float* Wk       = (const float*)d_in[9];
  const float* bk       = (const float*)d_in[10];
  const float* Wv       = (const float*)d_in[11];
  const float* bv       = (const float*)d_in[12];
  const float* Wo       = (const float*)d_in[13];
  const float* bo       = (const float*)d_in[14];
  float* out = (float*)d_out;

  char* ws = (char*)d_ws;
  size_t off = 0;
  auto alloc = [&](size_t bytes) -> char* {
    char* p = ws + off;
    off += (bytes + 255) & ~size_t(255);
    return p;
  };
  float*    keys  = (float*)   alloc((size_t)8192 * 256 * 4);
  float*    vals  = (float*)   alloc((size_t)8192 * 256 * 4);
  float*    K2    = (float*)   alloc((size_t)8192 * 256 * 4);
  float*    E     = (float*)   alloc((size_t)2048 * 1024 * 4);
  float*    WqT   = (float*)   alloc((size_t)256 * 256 * 4);
  float*    sb    = (float*)   alloc((size_t)8192 * 4);
  float*    bsum  = (float*)   alloc((size_t)1024 * 4);
  float*    hcbuf = (float*)   alloc((size_t)2048 * 512 * 4);
  ushort*   hcb16 = (ushort*)  alloc((size_t)2048 * 512 * 2);
  float*    hglob = (float*)   alloc((size_t)2 * 16 * 256 * 4);
  float*    mp    = (float*)   alloc((size_t)16 * 8 * 4);
  float*    lp    = (float*)   alloc((size_t)16 * 8 * 4);
  unsigned* up_p  = (unsigned*)alloc((size_t)16 * 8 * 128 * 4);
  unsigned* flagA = (unsigned*)alloc((size_t)128 * 4);
  unsigned* flagC = (unsigned*)alloc((size_t)128 * 4);

  hipMemsetAsync(flagA, 0, 128 * 4, stream);
  hipMemsetAsync(flagC, 0, 128 * 4, stream);

  prep_kernel<<<260, 256, 0, stream>>>(Wq, WqT, b_ih, b_hh, bsum);

  gemm_kernel<true, false><<<dim3(64, 2), 256, 0, stream>>>(features, 512, nullptr, Wk, 512, bk, keys, 256, 512);
  gemm_kernel<true, false><<<dim3(64, 2), 256, 0, stream>>>(features, 512, nullptr, Wv, 512, bv, vals, 256, 512);
  gemm_kernel<true, false><<<dim3(64, 2), 256, 0, stream>>>(keys, 256, nullptr, WqT, 256, nullptr, K2, 256, 256);
  sb_kernel<<<2048, 256, 0, stream>>>(keys, bq, sb);
  gemm_kernel<true, false><<<dim3(16, 8), 256, 0, stream>>>(emb, 256, inputs, W_ih, 512, bsum, E, 1024, 256);

  hipFuncSetAttribute(reinterpret_cast<const void*>(scan_kernel),
                      hipFuncAttributeMaxDynamicSharedMemorySize, (int)sizeof(ScanSmem));
  scan_kernel<<<NG, 256, sizeof(ScanSmem), stream>>>(E, K2, sb, vals, W_ih, W_hh,
                                                     hcbuf, hglob, mp, lp, up_p, flagA, flagC);

  cvt_kernel<<<1024, 256, 0, stream>>>(hcbuf, hcb16, 2048 * 512 / 4);

  gemm_kernel<false, true><<<dim3(16, 250), 256, 0, stream>>>(hcb16, 512, nullptr, Wo, 512, bo, out, 32000, 512);
}